// Round 6
// baseline (141.092 us; speedup 1.0000x reference)
//
#include <hip/hip_runtime.h>
#include <math.h>

#define NROWS 16384
#define DT_C 0.01f

typedef short s16x8 __attribute__((ext_vector_type(8)));
typedef float f32x4 __attribute__((ext_vector_type(4)));
typedef float f32x2 __attribute__((ext_vector_type(2)));

__device__ __forceinline__ unsigned short f2bf(float f) {
    unsigned u = __float_as_uint(f);
    u += 0x7fffu + ((u >> 16) & 1u);
    return (unsigned short)(u >> 16);
}
__device__ __forceinline__ unsigned pack2bf(float a, float b) {
    return (unsigned)f2bf(a) | ((unsigned)f2bf(b) << 16);
}
// VALU-pipe cross-lane adds via DPP. quad_perm xor1=0xB1, xor2=0x4E,
// row_half_mirror=0x141 (i^7 within 8).
template <int CTRL>
__device__ __forceinline__ float dppadd(float v) {
    int x = __builtin_amdgcn_update_dpp(0, __float_as_int(v), CTRL, 0xF, 0xF, true);
    return v + __int_as_float(x);
}
__device__ __forceinline__ float sum4(float p) {   // across lanes i, i^1, i^2, i^3
    p = dppadd<0xB1>(p);
    p = dppadd<0x4E>(p);
    return p;
}
__device__ __forceinline__ float sum8(float p) {
    p = dppadd<0xB1>(p);
    p = dppadd<0x4E>(p);
    p = dppadd<0x141>(p);
    return p;
}

// ---------------------------------------------------------------------------
// Prep: pack stage-B weights to bf16 flat [stage][k8][n][8] (k = k8*8+j).
// s=0: W_feat1[0:256], s=1: W_feat2, s=2: [W_xim1 | W_xil1].
// ---------------------------------------------------------------------------
__global__ __launch_bounds__(256) void prep_k(
    const float* __restrict__ Wf1, const float* __restrict__ Wf2,
    const float* __restrict__ Wm1, const float* __restrict__ Wl1,
    const float* __restrict__ bm1, const float* __restrict__ bl1,
    unsigned short* __restrict__ wpack, float* __restrict__ biasH)
{
    const int id = blockIdx.x * 256 + threadIdx.x;   // 0..24575
    const int n  = id & 255;
    const int k8 = (id >> 8) & 31;
    const int s  = id >> 13;

    unsigned short tmp[8];
    #pragma unroll
    for (int j = 0; j < 8; ++j) {
        const int k = k8 * 8 + j;
        float v;
        if (s == 0)      v = Wf1[k * 256 + n];
        else if (s == 1) v = Wf2[k * 256 + n];
        else             v = (n < 128) ? Wm1[k * 128 + n] : Wl1[k * 128 + n - 128];
        tmp[j] = f2bf(v);
    }
    *(uint4*)&wpack[((s * 32 + k8) * 256 + n) * 8] = *(const uint4*)tmp;

    if (id < 256) biasH[id] = (id < 128) ? bm1[id] : bl1[id - 128];
}

// ---------------------------------------------------------------------------
// Mega kernel (xi production), per 32-row block:
//   data -> LDS frags; MFMA h1 -> feat -> heads (B direct from L2 wpack);
//   per-row 128-dots -> out_mean / out_lnvar / xi_ws.
// ---------------------------------------------------------------------------
__global__ __launch_bounds__(256, 2) void mega_k(
    const float* __restrict__ data, const float* __restrict__ omega,
    const float* __restrict__ eps_g,
    const unsigned short* __restrict__ wpack, const float* __restrict__ biasH,
    const float* __restrict__ bf1, const float* __restrict__ bf2,
    const float* __restrict__ w256g,
    const float* __restrict__ Wm2, const float* __restrict__ bm2,
    const float* __restrict__ Wl2, const float* __restrict__ bl2,
    float* __restrict__ out_mean, float* __restrict__ out_lnvar,
    float* __restrict__ xi_ws)
{
    __shared__ __align__(16) unsigned char smem[32896];
    unsigned short* As1 = (unsigned short*)smem;            // 16KB frags: data, then feat
    unsigned short* Hs  = (unsigned short*)(smem + 16384);  // 16KB frags: h1
    float* headsF = (float*)smem;                           // 32KB alias: heads f32
    float* omg = (float*)(smem + 32768);                    // 32 floats

    const int tid  = threadIdx.x;
    const int wid  = tid >> 6;
    const int lane = tid & 63;
    const int ln   = lane & 15;
    const int quad = lane >> 4;
    const int r0   = blockIdx.x * 32;

    // ---- stage data -> As1 (coalesced, swizzled frag pack)
    {
        #pragma unroll
        for (int g2 = 0; g2 < 8; ++g2) {
            const int unit = g2 * 256 + tid;     // 16B unit over 32x256 f32
            const int m    = unit >> 6;
            const int c16  = unit & 63;
            const int kblk = c16 >> 1;
            const int h    = c16 & 1;
            const float4 v = *(const float4*)&data[(size_t)(r0 + m) * 256 + c16 * 4];
            unsigned* d = (unsigned*)&As1[((kblk * 32) + (m ^ (kblk & 7))) * 8 + h * 4];
            d[0] = pack2bf(v.x, v.y);
            d[1] = pack2bf(v.z, v.w);
        }
        if (tid < 32) omg[tid] = omega[r0 + tid];
    }

    f32x4 acc[2][4];

    auto seed = [&](const float* bias) {
        #pragma unroll
        for (int nt = 0; nt < 4; ++nt) {
            const float b = bias[wid * 64 + nt * 16 + ln];
            acc[0][nt] = f32x4{b, b, b, b};
            acc[1][nt] = acc[0][nt];
        }
    };

    // A-frags from LDS, B-frags straight from global (L2-resident)
    auto run_stage = [&](const unsigned short* Ap, const unsigned short* wp) {
        #pragma unroll
        for (int c = 0; c < 4; ++c) {
            #pragma unroll
            for (int kk = 0; kk < 2; ++kk) {
                const int kb   = kk * 4 + quad;
                const int kblk = c * 8 + kb;
                const int f    = kblk & 7;
                s16x8 b0 = *(const s16x8*)&wp[((size_t)(kblk * 256) + wid * 64 + 0 * 16 + ln) * 8];
                s16x8 b1 = *(const s16x8*)&wp[((size_t)(kblk * 256) + wid * 64 + 1 * 16 + ln) * 8];
                s16x8 b2 = *(const s16x8*)&wp[((size_t)(kblk * 256) + wid * 64 + 2 * 16 + ln) * 8];
                s16x8 b3 = *(const s16x8*)&wp[((size_t)(kblk * 256) + wid * 64 + 3 * 16 + ln) * 8];
                s16x8 a0 = *(const s16x8*)&Ap[(kblk * 32 + (ln ^ f)) * 8];
                s16x8 a1 = *(const s16x8*)&Ap[(kblk * 32 + ((ln ^ f) + 16)) * 8];
                acc[0][0] = __builtin_amdgcn_mfma_f32_16x16x32_bf16(a0, b0, acc[0][0], 0, 0, 0);
                acc[1][0] = __builtin_amdgcn_mfma_f32_16x16x32_bf16(a1, b0, acc[1][0], 0, 0, 0);
                acc[0][1] = __builtin_amdgcn_mfma_f32_16x16x32_bf16(a0, b1, acc[0][1], 0, 0, 0);
                acc[1][1] = __builtin_amdgcn_mfma_f32_16x16x32_bf16(a1, b1, acc[1][1], 0, 0, 0);
                acc[0][2] = __builtin_amdgcn_mfma_f32_16x16x32_bf16(a0, b2, acc[0][2], 0, 0, 0);
                acc[1][2] = __builtin_amdgcn_mfma_f32_16x16x32_bf16(a1, b2, acc[1][2], 0, 0, 0);
                acc[0][3] = __builtin_amdgcn_mfma_f32_16x16x32_bf16(a0, b3, acc[0][3], 0, 0, 0);
                acc[1][3] = __builtin_amdgcn_mfma_f32_16x16x32_bf16(a1, b3, acc[1][3], 0, 0, 0);
            }
        }
    };

    auto write_packed = [&](unsigned short* dst, bool addOm) {
        #pragma unroll
        for (int nt = 0; nt < 4; ++nt) {
            const int col = wid * 64 + nt * 16 + ln;
            const int kg  = col >> 3, f = kg & 7, jj = col & 7;
            const float wo = addOm ? w256g[col] : 0.f;
            #pragma unroll
            for (int mt = 0; mt < 2; ++mt) {
                #pragma unroll
                for (int r = 0; r < 4; ++r) {
                    const int row = mt * 16 + quad * 4 + r;
                    float v = acc[mt][nt][r];
                    if (addOm) v = fmaf(omg[row], wo, v);
                    v = fmaxf(v, 0.f);
                    dst[(kg * 32 + (row ^ f)) * 8 + jj] = f2bf(v);
                }
            }
        }
    };

    __syncthreads();                               // B0: As1 + omg ready
    seed(bf1);
    run_stage(As1, wpack);
    write_packed(Hs, true);
    __syncthreads();                               // B1: Hs ready
    seed(bf2);
    run_stage(Hs, wpack + 65536);
    write_packed(As1, false);
    __syncthreads();                               // B2: As1(feat) ready
    seed(biasH);
    run_stage(As1, wpack + 131072);
    __syncthreads();                               // B3a: all waves done with As1/Hs (alias!)
    #pragma unroll
    for (int nt = 0; nt < 4; ++nt) {
        const int col = wid * 64 + nt * 16 + ln;
        #pragma unroll
        for (int mt = 0; mt < 2; ++mt) {
            #pragma unroll
            for (int r = 0; r < 4; ++r) {
                const int row = mt * 16 + quad * 4 + r;
                headsF[row * 256 + ((col + row * 8) & 255)] = fmaxf(acc[mt][nt][r], 0.f);
            }
        }
    }
    __syncthreads();                               // B3: heads ready

    // ---- 128-dot heads: 8 lanes/row -> xi_mean / xi_lnvar / xi
    {
        const int m = tid >> 3, l = tid & 7;
        float pm = 0.f, pl = 0.f;
        #pragma unroll
        for (int q = 0; q < 4; ++q) {
            const int c0 = l * 16 + q * 4;
            const float4 hm = *(const float4*)&headsF[m * 256 + ((c0 + m * 8) & 255)];
            const float4 wm = *(const float4*)&Wm2[c0];
            const float4 hl = *(const float4*)&headsF[m * 256 + ((128 + c0 + m * 8) & 255)];
            const float4 wl = *(const float4*)&Wl2[c0];
            pm = fmaf(hm.w, wm.w, fmaf(hm.z, wm.z, fmaf(hm.y, wm.y, fmaf(hm.x, wm.x, pm))));
            pl = fmaf(hl.w, wl.w, fmaf(hl.z, wl.z, fmaf(hl.y, wl.y, fmaf(hl.x, wl.x, pl))));
        }
        pm = sum8(pm);
        pl = sum8(pl);
        if (l == 0) {
            const float xm   = pm + bm2[0];
            const float mean = fmaxf(xm, 0.f) + log1pf(expf(-fabsf(xm)));
            const float lnv  = pl + bl2[0];
            out_mean[r0 + m]  = mean;
            out_lnvar[r0 + m] = lnv;
            float xi = mean + expf(0.5f * lnv) * eps_g[r0 + m];
            xi_ws[r0 + m] = fminf(fmaxf(xi, 0.f), 1.f);
        }
    }
}

// ---------------------------------------------------------------------------
// ODE scan + inline decay. 4 lanes/row x 16 units/lane, 64 rows/block,
// 256 blocks -> exactly 1 wave/SIMD device-wide. Verlet form; decay applied
// at capture (xi known). Output flushed as float4 per lane every 16 steps.
// ---------------------------------------------------------------------------
__global__ __launch_bounds__(256) void ode2_k(
    const float* __restrict__ data, const float* __restrict__ omega_g,
    const float* __restrict__ xi_ws,
    const float* __restrict__ Wa1, const float* __restrict__ ba1,
    const float* __restrict__ Wa2, const float* __restrict__ ba2,
    float* __restrict__ xout)
{
    const int tid = threadIdx.x;
    const int r   = tid >> 2;    // row in block 0..63
    const int l   = tid & 3;     // lane in row
    const int row = blockIdx.x * 64 + r;

    const float om = omega_g[row];
    const float xi = xi_ws[row];
    const float s  = expf(-xi * DT_C);
    const float pseed = ba2[0] * 0.25f;

    // 16 units per lane: u = l*16 + i*2 + {0,1}
    f32x2 w1v[8], Av[8], w2v[8];
    #pragma unroll
    for (int i = 0; i < 8; ++i) {
        const int u = l * 16 + i * 2;
        const f32x2 w0 = *(const f32x2*)&Wa1[u];
        const f32x2 bb = *(const f32x2*)&ba1[u];
        w1v[i] = *(const f32x2*)&Wa1[64 + u];
        w2v[i] = *(const f32x2*)&Wa2[u];
        Av[i]  = f32x2{fmaf(om, w0.x, bb.x), fmaf(om, w0.y, bb.y)};
    }

    auto partial = [&](float y) -> float {
        const f32x2 y2 = f32x2{y, y};
        f32x2 a0 = f32x2{pseed, 0.f};
        f32x2 a1 = f32x2{0.f, 0.f};
        f32x2 a2 = f32x2{0.f, 0.f};
        f32x2 a3 = f32x2{0.f, 0.f};
        #pragma unroll
        for (int i = 0; i < 8; ++i) {
            f32x2 h = __builtin_elementwise_fma(y2, w1v[i], Av[i]);
            h = __builtin_elementwise_max(h, f32x2{0.f, 0.f});
            if ((i & 3) == 0) a0 = __builtin_elementwise_fma(h, w2v[i], a0);
            if ((i & 3) == 1) a1 = __builtin_elementwise_fma(h, w2v[i], a1);
            if ((i & 3) == 2) a2 = __builtin_elementwise_fma(h, w2v[i], a2);
            if ((i & 3) == 3) a3 = __builtin_elementwise_fma(h, w2v[i], a3);
        }
        a0 = a0 + a1;
        a2 = a2 + a3;
        a0 = a0 + a2;
        return a0.x + a0.y;
    };

    const float y0 = data[(size_t)row * 256];
    float ym = y0;          // y_t
    float yc = y0;          // y_{t+1}  (v0 = 0)
    const float DT2 = DT_C * DT_C;
    float pr = sum4(partial(ym));
    float d = 1.f;

    float* orow = xout + (size_t)row * 256 + l * 4;
    for (int b = 0; b < 16; ++b) {
        float cur[4] = {0.f, 0.f, 0.f, 0.f};
        #pragma unroll
        for (int j = 0; j < 16; ++j) {
            const float m_ = d * ym;
            if ((j >> 2) == l) cur[j & 3] = m_;    // cmp hoists; 1 cndmask/step
            d *= s;
            float pn = sum4(partial(yc));
            const float ynext = fmaf(DT2, pr, fmaf(2.f, yc, -ym));
            ym = yc; yc = ynext; pr = pn;          // pr consumed next step
        }
        *(float4*)&orow[b * 16] = *(const float4*)cur;
    }
}

// ---------------------------------------------------------------------------
extern "C" void kernel_launch(void* const* d_in, const int* in_sizes, int n_in,
                              void* d_out, int out_size, void* d_ws, size_t ws_size,
                              hipStream_t stream)
{
    const float* data    = (const float*)d_in[0];
    const float* omega   = (const float*)d_in[1];
    const float* eps     = (const float*)d_in[2];
    const float* W_feat1 = (const float*)d_in[3];
    const float* b_feat1 = (const float*)d_in[4];
    const float* W_feat2 = (const float*)d_in[5];
    const float* b_feat2 = (const float*)d_in[6];
    const float* W_xim1  = (const float*)d_in[7];
    const float* b_xim1  = (const float*)d_in[8];
    const float* W_xim2  = (const float*)d_in[9];
    const float* b_xim2  = (const float*)d_in[10];
    const float* W_xil1  = (const float*)d_in[11];
    const float* b_xil1  = (const float*)d_in[12];
    const float* W_xil2  = (const float*)d_in[13];
    const float* b_xil2  = (const float*)d_in[14];
    const float* W_aux1  = (const float*)d_in[15];
    const float* b_aux1  = (const float*)d_in[16];
    const float* W_aux2  = (const float*)d_in[17];
    const float* b_aux2  = (const float*)d_in[18];

    float* out_mean  = (float*)d_out;
    float* out_lnvar = out_mean + NROWS;
    float* out_x     = out_lnvar + NROWS;

    unsigned short* wpack = (unsigned short*)d_ws;           // 384KB bf16
    float* biasH = (float*)((char*)d_ws + 3 * 32 * 256 * 8 * 2);
    float* xi_ws = biasH + 256;                              // N floats

    prep_k<<<96, 256, 0, stream>>>(W_feat1, W_feat2, W_xim1, W_xil1,
                                   b_xim1, b_xil1, wpack, biasH);
    mega_k<<<512, 256, 0, stream>>>(data, omega, eps, wpack, biasH,
                                    b_feat1, b_feat2, W_feat1 + 256 * 256,
                                    W_xim2, b_xim2, W_xil2, b_xil2,
                                    out_mean, out_lnvar, xi_ws);
    ode2_k<<<256, 256, 0, stream>>>(data, omega, xi_ws,
                                    W_aux1, b_aux1, W_aux2, b_aux2, out_x);
}